// Round 3
// baseline (254.077 us; speedup 1.0000x reference)
//
#include <hip/hip_runtime.h>

typedef __bf16 bf16;
typedef __bf16 bf16x8 __attribute__((ext_vector_type(8)));
typedef __bf16 bf16x4 __attribute__((ext_vector_type(4)));
typedef float f32x4 __attribute__((ext_vector_type(4)));

#define MFMA(a, b, c) __builtin_amdgcn_mfma_f32_16x16x32_bf16((a), (b), (c), 0, 0, 0)

static __device__ __forceinline__ f32x4 zero4() {
    f32x4 z; z[0] = 0.f; z[1] = 0.f; z[2] = 0.f; z[3] = 0.f; return z;
}

// ---------------- fused prep: all f32->bf16 conversions, one launch ----------------
__global__ __launch_bounds__(256) void k_prep(
    const float* __restrict__ x, const float* __restrict__ xsp,
    const float* __restrict__ Wx, const float* __restrict__ Wy, const float* __restrict__ Wz,
    const float* __restrict__ W3,
    bf16* __restrict__ xb, bf16* __restrict__ xspb, bf16* __restrict__ wbf,
    bf16* __restrict__ w3b, float* __restrict__ w3bias)
{
    const int b = blockIdx.x, t = threadIdx.x;
    if (b < 1120) {
        const float* src; bf16* dst; int base;
        if (b < 512)       { src = xsp; dst = xspb; base = b * 4096; }
        else if (b < 1024) { src = x;   dst = xb;   base = (b - 512) * 4096; }
        else {
            int i = b - 1024;
            int proj = i >> 5;
            src = (proj == 0) ? Wx : (proj == 1) ? Wy : Wz;
            dst = wbf + proj * 131072;
            base = (i & 31) * 4096;
        }
        int o = base + t * 16;
#pragma unroll
        for (int u = 0; u < 4; u++) {
            float4 v = *(const float4*)(src + o + u * 4);
            bf16x4 w; w[0] = (bf16)v.x; w[1] = (bf16)v.y; w[2] = (bf16)v.z; w[3] = (bf16)v.w;
            *(bf16x4*)(dst + o + u * 4) = w;
        }
    } else {
        int nb = b - 1120;                   // 0..2063
        int n = nb * 8 + (t >> 5);           // row of W3 (i*128+k), < 16512
        int c = t & 31;
        const float* row = W3 + n * 129;
        bf16x4 w;
        w[0] = (bf16)row[4 * c + 0];
        w[1] = (bf16)row[4 * c + 1];
        w[2] = (bf16)row[4 * c + 2];
        w[3] = (bf16)row[4 * c + 3];
        *(bf16x4*)(w3b + n * 136 + 4 * c) = w;
        if (c == 0) w3bias[n] = row[128];
    }
}

// ---------------- MLP: pout[proj][m][p] = leaky_relu(A @ W^T + b) ----------------
__global__ __launch_bounds__(256) void k_mlp(
    const bf16* __restrict__ xspb, const bf16* __restrict__ xb,
    const bf16* __restrict__ wbf,
    const float* __restrict__ bx, const float* __restrict__ by, const float* __restrict__ bz,
    bf16* __restrict__ pout)
{
    const int proj = blockIdx.y;
    const bf16* A = (proj == 2) ? xb : xspb;
    const bf16* W = wbf + proj * 131072;
    const float* bias = (proj == 0) ? bx : (proj == 1) ? by : bz;
    bf16* out = pout + proj * 262144;

    const int tid = threadIdx.x;
    const int wv = tid >> 6, lane = tid & 63, quad = lane >> 4, lr = lane & 15;
    const int m0 = blockIdx.x * 16;

    f32x4 acc[2];
    acc[0] = zero4(); acc[1] = zero4();

    const bf16* brow = A + (m0 + lr) * 1024 + quad * 8;
    const bf16* arow = W + (wv * 16 + lr) * 1024 + quad * 8;

#pragma unroll 4
    for (int kw = 0; kw < 32; kw++) {
        bf16x8 bfr = *(const bf16x8*)(brow + kw * 32);
        bf16x8 a0 = *(const bf16x8*)(arow + kw * 32);
        bf16x8 a1 = *(const bf16x8*)(arow + 65536 + kw * 32);
        acc[0] = MFMA(a0, bfr, acc[0]);
        acc[1] = MFMA(a1, bfr, acc[1]);
    }
#pragma unroll
    for (int s = 0; s < 2; s++) {
        int p = (wv + s * 4) * 16 + quad * 4;
        float4 bv = *(const float4*)(bias + p);
        int m = m0 + lr;
        bf16x4 o;
        float v0 = acc[s][0] + bv.x; o[0] = (bf16)(v0 > 0.f ? v0 : 0.1f * v0);
        float v1 = acc[s][1] + bv.y; o[1] = (bf16)(v1 > 0.f ? v1 : 0.1f * v1);
        float v2 = acc[s][2] + bv.z; o[2] = (bf16)(v2 > 0.f ? v2 : 0.1f * v2);
        float v3 = acc[s][3] + bv.w; o[3] = (bf16)(v3 > 0.f ? v3 : 0.1f * v3);
        *(bf16x4*)(out + m * 128 + p) = o;
    }
}

// ---------------- V[b][y][n=(i*128+k)] = sum_j yp[b,y,j]*W3[n,j] + w3bias[n] ----------------
__global__ __launch_bounds__(256, 4) void k_vgemm(
    const bf16* __restrict__ yp,     // [16][128][128]
    const bf16* __restrict__ w3b,    // [16512][136]
    const float* __restrict__ w3bias,// [16512]
    bf16* __restrict__ V)            // [16][128][16512]
{
    __shared__ bf16 Vt[128 * 136];   // [y][n_local], ld=136
    const int b = blockIdx.y;
    const int n0 = blockIdx.x * 128;
    const int tid = threadIdx.x;
    const int wv = tid >> 6, lane = tid & 63, quad = lane >> 4, lr = lane & 15;
    const int y0 = wv * 32;

    const bf16* Ab = yp + b * 16384;

    f32x4 acc[8][2];
#pragma unroll
    for (int nt = 0; nt < 8; nt++) { acc[nt][0] = zero4(); acc[nt][1] = zero4(); }

#pragma unroll
    for (int kw = 0; kw < 4; kw++) {
        bf16x8 b0 = *(const bf16x8*)(Ab + (y0 + lr) * 128 + kw * 32 + quad * 8);
        bf16x8 b1 = *(const bf16x8*)(Ab + (y0 + 16 + lr) * 128 + kw * 32 + quad * 8);
#pragma unroll
        for (int nt = 0; nt < 8; nt++) {
            bf16x8 af = *(const bf16x8*)(w3b + (n0 + nt * 16 + lr) * 136 + kw * 32 + quad * 8);
            acc[nt][0] = MFMA(af, b0, acc[nt][0]);
            acc[nt][1] = MFMA(af, b1, acc[nt][1]);
        }
    }
#pragma unroll
    for (int nt = 0; nt < 8; nt++) {
        int nl = nt * 16 + quad * 4;
        float4 bv = *(const float4*)(w3bias + n0 + nl);
#pragma unroll
        for (int s = 0; s < 2; s++) {
            int y = y0 + s * 16 + lr;
            bf16x4 o;
            o[0] = (bf16)(acc[nt][s][0] + bv.x);
            o[1] = (bf16)(acc[nt][s][1] + bv.y);
            o[2] = (bf16)(acc[nt][s][2] + bv.z);
            o[3] = (bf16)(acc[nt][s][3] + bv.w);
            *(bf16x4*)(&Vt[y * 136 + nl]) = o;
        }
    }
    __syncthreads();
    const int yr = tid >> 4, nn = (tid & 15) * 8;
#pragma unroll
    for (int pass = 0; pass < 8; pass++) {
        int y = pass * 16 + yr;
        bf16x8 v = *(const bf16x8*)(&Vt[y * 136 + nn]);
        *(bf16x8*)(V + (b * 128 + y) * 16512 + n0 + nn) = v;
    }
}

// ---------------- k_score: persistent blocks, double-buffered V staging ----------------
// grid 512 = exactly 2 blocks/CU. Block p owns 4 consecutive it = 4p..4p+3:
// b = it>>7 is CONSTANT per block (4p mod 128 <= 124) -> zp/xp fragments loaded once;
// V rows are 4 contiguous 33KB streams. Next V row prefetched into regs before the
// top barrier, ds_written to the other LDS buffer after GEMM1 -> stage latency hidden.
// LDS 2*35.1KB + Hb = 70.7KB/block -> 141KB/CU at 2 blocks/CU (gfx950 has 160KB).
__global__ __launch_bounds__(512, 4) void k_score(
    const bf16* __restrict__ xp,    // [16][128][128]
    const bf16* __restrict__ zp,    // [16][128][128]
    const bf16* __restrict__ V,     // [16][128][16512]
    float* __restrict__ out)        // [16][128][128][128]  (b,x,y,z)
{
    __shared__ __align__(16) bf16 Vl[2][129 * 136];  // V tile [i][k] / H tile [z][i]
    __shared__ float Hb[128];                        // H[z][128]
    const int tid = threadIdx.x;
    const int wv = tid >> 6, lane = tid & 63, quad = lane >> 4, lr = lane & 15;
    const int r0 = wv * 16 + lr;                     // wave-owned row (z in G1, x in G2)

    const int it0 = blockIdx.x * 4;
    const int b = it0 >> 7;                          // constant for all 4 iterations
    const int y0 = it0 & 127;                        // y = y0 + n

    const bf16* Zb = zp + b * 16384;
    const bf16* Xb = xp + b * 16384;
    const bf16* Vbase = V + (b * 128 + y0) * 16512;

    // ---- stage iteration 0 into buf 0 (loads issued before fragment loads) ----
    bf16x8 st[4];
#pragma unroll
    for (int u = 0; u < 4; u++) st[u] = *(const bf16x8*)(Vbase + (tid + u * 512) * 8);
    bf16x8 st4;
#pragma unroll
    for (int q = 0; q < 8; q++) st4[q] = (bf16)0.f;
    if (tid < 16) st4 = *(const bf16x8*)(Vbase + (2048 + tid) * 8);

    // loop-invariant zp/xp fragments (b fixed for the whole block)
    bf16x8 bz[4], bxf[4];
#pragma unroll
    for (int kw = 0; kw < 4; kw++) bz[kw] = *(const bf16x8*)(Zb + r0 * 128 + kw * 32 + quad * 8);
#pragma unroll
    for (int iw = 0; iw < 4; iw++) bxf[iw] = *(const bf16x8*)(Xb + r0 * 128 + iw * 32 + quad * 8);

#pragma unroll
    for (int u = 0; u < 4; u++) {
        int c = tid + u * 512;
        *(bf16x8*)(&Vl[0][(c >> 4) * 136 + (c & 15) * 8]) = st[u];
    }
    if (tid < 16) *(bf16x8*)(&Vl[0][128 * 136 + tid * 8]) = st4;

#pragma unroll 1
    for (int n = 0; n < 4; n++) {
        const int cb = n & 1;
        const bf16* Vc = &Vl[cb][0];       // current V tile (becomes H tile)
        bf16* Vn = &Vl[cb ^ 1][0];         // next V tile destination

        // prefetch next V row into regs (latency hidden under GEMM1)
        if (n < 3) {
            const bf16* Vnx = Vbase + (n + 1) * 16512;
#pragma unroll
            for (int u = 0; u < 4; u++) st[u] = *(const bf16x8*)(Vnx + (tid + u * 512) * 8);
            if (tid < 16) st4 = *(const bf16x8*)(Vnx + (2048 + tid) * 8);
        }
        __syncthreads();   // buf cb fully staged; previous iteration fully retired

        // ---- GEMM1: D[row=i][col=z], wave owns z in [wv*16, wv*16+16) ----
        f32x4 acc1[9];
#pragma unroll
        for (int it = 0; it < 9; it++) acc1[it] = zero4();

#pragma unroll
        for (int kw = 0; kw < 4; kw++) {
#pragma unroll
            for (int it = 0; it < 8; it++) {
                bf16x8 af = *(const bf16x8*)(Vc + (it * 16 + lr) * 136 + kw * 32 + quad * 8);
                acc1[it] = MFMA(af, bz[kw], acc1[it]);
            }
            bf16x8 a8;
#pragma unroll
            for (int q = 0; q < 8; q++) a8[q] = (bf16)0.f;
            if (lr == 0) a8 = *(const bf16x8*)(Vc + 128 * 136 + kw * 32 + quad * 8);
            acc1[8] = MFMA(a8, bz[kw], acc1[8]);
        }

        // write the prefetched V row into the other buffer (overlaps tail of GEMM1 on
        // other waves; Vn's previous readers all retired at the top barrier)
        if (n < 3) {
#pragma unroll
            for (int u = 0; u < 4; u++) {
                int c = tid + u * 512;
                *(bf16x8*)(Vn + (c >> 4) * 136 + (c & 15) * 8) = st[u];
            }
            if (tid < 16) *(bf16x8*)(Vn + 128 * 136 + tid * 8) = st4;
        }
        __syncthreads();   // all V reads of buf cb done; region reusable for H

        // H -> LDS (reg r = consecutive i), row stride 136
        bf16* Hc = &Vl[cb][0];
#pragma unroll
        for (int it = 0; it < 8; it++) {
            int i = it * 16 + quad * 4;
            bf16x4 o;
            o[0] = (bf16)acc1[it][0];
            o[1] = (bf16)acc1[it][1];
            o[2] = (bf16)acc1[it][2];
            o[3] = (bf16)acc1[it][3];
            *(bf16x4*)(Hc + r0 * 136 + i) = o;
        }
        if (quad == 0) Hb[r0] = acc1[8][0];   // bias row i=128 lives in D row 0
        __syncthreads();

        // ---- GEMM2: D[row=z][col=x], wave owns x in [wv*16, wv*16+16) ----
        f32x4 acc2[8];
#pragma unroll
        for (int zt = 0; zt < 8; zt++) acc2[zt] = zero4();

#pragma unroll
        for (int iw = 0; iw < 4; iw++) {
#pragma unroll
            for (int zt = 0; zt < 8; zt++) {
                bf16x8 ah = *(const bf16x8*)(Hc + (zt * 16 + lr) * 136 + iw * 32 + quad * 8);
                acc2[zt] = MFMA(ah, bxf[iw], acc2[zt]);
            }
        }
        // epilogue: f32x4 stores; y = y0 + n
#pragma unroll
        for (int zt = 0; zt < 8; zt++) {
            int zb = zt * 16 + quad * 4;
            f32x4 hb = *(const f32x4*)(&Hb[zb]);
            f32x4 o;
            o[0] = acc2[zt][0] + hb[0];
            o[1] = acc2[zt][1] + hb[1];
            o[2] = acc2[zt][2] + hb[2];
            o[3] = acc2[zt][3] + hb[3];
            *(f32x4*)(out + (((b * 128 + r0) * 128 + (y0 + n)) * 128 + zb)) = o;
        }
    }
}

extern "C" void kernel_launch(void* const* d_in, const int* in_sizes, int n_in,
                              void* d_out, int out_size, void* d_ws, size_t ws_size,
                              hipStream_t stream) {
    const float* x   = (const float*)d_in[0];
    const float* xsp = (const float*)d_in[1];
    const float* Wx  = (const float*)d_in[2];
    const float* bx  = (const float*)d_in[3];
    const float* Wy  = (const float*)d_in[4];
    const float* by  = (const float*)d_in[5];
    const float* Wz  = (const float*)d_in[6];
    const float* bz  = (const float*)d_in[7];
    const float* W3  = (const float*)d_in[8];
    float* out = (float*)d_out;

    char* ws = (char*)d_ws;
    bf16*  xspb   = (bf16*)(ws);                   // 4 MiB
    bf16*  xb     = (bf16*)(ws + 4194304);         // 4 MiB
    bf16*  wbf    = (bf16*)(ws + 8388608);         // 768 KiB
    bf16*  w3b    = (bf16*)(ws + 9175040);         // 16512*136*2 = 4.28 MiB
    bf16*  pout   = (bf16*)(ws + 13666304);        // 3*2048*128*2 = 1.5 MiB (xp,yp,zp)
    bf16*  V      = (bf16*)(ws + 15239168);        // 16*128*16512*2 = 64.5 MiB
    float* w3bias = (float*)(ws + 82872320);       // 66 KB

    k_prep<<<3184, 256, 0, stream>>>(x, xsp, Wx, Wy, Wz, W3, xb, xspb, wbf, w3b, w3bias);
    k_mlp<<<dim3(128, 3), 256, 0, stream>>>(xspb, xb, wbf, bx, by, bz, pout);
    k_vgemm<<<dim3(129, 16), 256, 0, stream>>>(pout + 262144 /*yp*/, w3b, w3bias, V);
    k_score<<<512, 512, 0, stream>>>(pout /*xp*/, pout + 524288 /*zp*/, V, out);
}

// Round 4
// 252.258 us; speedup vs baseline: 1.0072x; 1.0072x over previous
//
#include <hip/hip_runtime.h>

typedef __bf16 bf16;
typedef __bf16 bf16x8 __attribute__((ext_vector_type(8)));
typedef __bf16 bf16x4 __attribute__((ext_vector_type(4)));
typedef float f32x4 __attribute__((ext_vector_type(4)));

#define MFMA(a, b, c) __builtin_amdgcn_mfma_f32_16x16x32_bf16((a), (b), (c), 0, 0, 0)

static __device__ __forceinline__ f32x4 zero4() {
    f32x4 z; z[0] = 0.f; z[1] = 0.f; z[2] = 0.f; z[3] = 0.f; return z;
}

// Barrier with LDS-only drain: all cross-wave deps at these barriers are LDS
// (V-tile stage, H-tile, Hb). Global loads are consumed by the SAME wave's
// ds_write (compiler inserts the vmcnt wait there); global stores are never
// read back. So lgkmcnt(0)+s_barrier is sufficient -- and it leaves the
// epilogue stores + prefetch loads in flight across the barrier, unlike
// __syncthreads() which drains vmcnt(0) and serializes them.
static __device__ __forceinline__ void soft_barrier() {
    __builtin_amdgcn_sched_barrier(0);
    asm volatile("s_waitcnt lgkmcnt(0)" ::: "memory");
    __builtin_amdgcn_s_barrier();
    __builtin_amdgcn_sched_barrier(0);
}

// ---------------- fused prep: all f32->bf16 conversions, one launch ----------------
__global__ __launch_bounds__(256) void k_prep(
    const float* __restrict__ x, const float* __restrict__ xsp,
    const float* __restrict__ Wx, const float* __restrict__ Wy, const float* __restrict__ Wz,
    const float* __restrict__ W3,
    bf16* __restrict__ xb, bf16* __restrict__ xspb, bf16* __restrict__ wbf,
    bf16* __restrict__ w3b, float* __restrict__ w3bias)
{
    const int b = blockIdx.x, t = threadIdx.x;
    if (b < 1120) {
        const float* src; bf16* dst; int base;
        if (b < 512)       { src = xsp; dst = xspb; base = b * 4096; }
        else if (b < 1024) { src = x;   dst = xb;   base = (b - 512) * 4096; }
        else {
            int i = b - 1024;
            int proj = i >> 5;
            src = (proj == 0) ? Wx : (proj == 1) ? Wy : Wz;
            dst = wbf + proj * 131072;
            base = (i & 31) * 4096;
        }
        int o = base + t * 16;
#pragma unroll
        for (int u = 0; u < 4; u++) {
            float4 v = *(const float4*)(src + o + u * 4);
            bf16x4 w; w[0] = (bf16)v.x; w[1] = (bf16)v.y; w[2] = (bf16)v.z; w[3] = (bf16)v.w;
            *(bf16x4*)(dst + o + u * 4) = w;
        }
    } else {
        int nb = b - 1120;                   // 0..2063
        int n = nb * 8 + (t >> 5);           // row of W3 (i*128+k), < 16512
        int c = t & 31;
        const float* row = W3 + n * 129;
        bf16x4 w;
        w[0] = (bf16)row[4 * c + 0];
        w[1] = (bf16)row[4 * c + 1];
        w[2] = (bf16)row[4 * c + 2];
        w[3] = (bf16)row[4 * c + 3];
        *(bf16x4*)(w3b + n * 136 + 4 * c) = w;
        if (c == 0) w3bias[n] = row[128];
    }
}

// ---------------- MLP: pout[proj][m][p] = leaky_relu(A @ W^T + b) ----------------
__global__ __launch_bounds__(256) void k_mlp(
    const bf16* __restrict__ xspb, const bf16* __restrict__ xb,
    const bf16* __restrict__ wbf,
    const float* __restrict__ bx, const float* __restrict__ by, const float* __restrict__ bz,
    bf16* __restrict__ pout)
{
    const int proj = blockIdx.y;
    const bf16* A = (proj == 2) ? xb : xspb;
    const bf16* W = wbf + proj * 131072;
    const float* bias = (proj == 0) ? bx : (proj == 1) ? by : bz;
    bf16* out = pout + proj * 262144;

    const int tid = threadIdx.x;
    const int wv = tid >> 6, lane = tid & 63, quad = lane >> 4, lr = lane & 15;
    const int m0 = blockIdx.x * 16;

    f32x4 acc[2];
    acc[0] = zero4(); acc[1] = zero4();

    const bf16* brow = A + (m0 + lr) * 1024 + quad * 8;
    const bf16* arow = W + (wv * 16 + lr) * 1024 + quad * 8;

#pragma unroll 4
    for (int kw = 0; kw < 32; kw++) {
        bf16x8 bfr = *(const bf16x8*)(brow + kw * 32);
        bf16x8 a0 = *(const bf16x8*)(arow + kw * 32);
        bf16x8 a1 = *(const bf16x8*)(arow + 65536 + kw * 32);
        acc[0] = MFMA(a0, bfr, acc[0]);
        acc[1] = MFMA(a1, bfr, acc[1]);
    }
#pragma unroll
    for (int s = 0; s < 2; s++) {
        int p = (wv + s * 4) * 16 + quad * 4;
        float4 bv = *(const float4*)(bias + p);
        int m = m0 + lr;
        bf16x4 o;
        float v0 = acc[s][0] + bv.x; o[0] = (bf16)(v0 > 0.f ? v0 : 0.1f * v0);
        float v1 = acc[s][1] + bv.y; o[1] = (bf16)(v1 > 0.f ? v1 : 0.1f * v1);
        float v2 = acc[s][2] + bv.z; o[2] = (bf16)(v2 > 0.f ? v2 : 0.1f * v2);
        float v3 = acc[s][3] + bv.w; o[3] = (bf16)(v3 > 0.f ? v3 : 0.1f * v3);
        *(bf16x4*)(out + m * 128 + p) = o;
    }
}

// ---------------- V[b][y][n=(i*128+k)] = sum_j yp[b,y,j]*W3[n,j] + w3bias[n] ----------------
__global__ __launch_bounds__(256, 4) void k_vgemm(
    const bf16* __restrict__ yp,     // [16][128][128]
    const bf16* __restrict__ w3b,    // [16512][136]
    const float* __restrict__ w3bias,// [16512]
    bf16* __restrict__ V)            // [16][128][16512]
{
    __shared__ bf16 Vt[128 * 136];   // [y][n_local], ld=136
    const int b = blockIdx.y;
    const int n0 = blockIdx.x * 128;
    const int tid = threadIdx.x;
    const int wv = tid >> 6, lane = tid & 63, quad = lane >> 4, lr = lane & 15;
    const int y0 = wv * 32;

    const bf16* Ab = yp + b * 16384;

    f32x4 acc[8][2];
#pragma unroll
    for (int nt = 0; nt < 8; nt++) { acc[nt][0] = zero4(); acc[nt][1] = zero4(); }

#pragma unroll
    for (int kw = 0; kw < 4; kw++) {
        bf16x8 b0 = *(const bf16x8*)(Ab + (y0 + lr) * 128 + kw * 32 + quad * 8);
        bf16x8 b1 = *(const bf16x8*)(Ab + (y0 + 16 + lr) * 128 + kw * 32 + quad * 8);
#pragma unroll
        for (int nt = 0; nt < 8; nt++) {
            bf16x8 af = *(const bf16x8*)(w3b + (n0 + nt * 16 + lr) * 136 + kw * 32 + quad * 8);
            acc[nt][0] = MFMA(af, b0, acc[nt][0]);
            acc[nt][1] = MFMA(af, b1, acc[nt][1]);
        }
    }
#pragma unroll
    for (int nt = 0; nt < 8; nt++) {
        int nl = nt * 16 + quad * 4;
        float4 bv = *(const float4*)(w3bias + n0 + nl);
#pragma unroll
        for (int s = 0; s < 2; s++) {
            int y = y0 + s * 16 + lr;
            bf16x4 o;
            o[0] = (bf16)(acc[nt][s][0] + bv.x);
            o[1] = (bf16)(acc[nt][s][1] + bv.y);
            o[2] = (bf16)(acc[nt][s][2] + bv.z);
            o[3] = (bf16)(acc[nt][s][3] + bv.w);
            *(bf16x4*)(&Vt[y * 136 + nl]) = o;
        }
    }
    __syncthreads();
    const int yr = tid >> 4, nn = (tid & 15) * 8;
#pragma unroll
    for (int pass = 0; pass < 8; pass++) {
        int y = pass * 16 + yr;
        bf16x8 v = *(const bf16x8*)(&Vt[y * 136 + nn]);
        *(bf16x8*)(V + (b * 128 + y) * 16512 + n0 + nn) = v;
    }
}

// ---------------- k_score: persistent blocks, soft-barrier software pipeline ----------------
// grid 512 = 2 blocks/CU. Block owns 4 consecutive (b,y): b constant -> zp/xp loaded once.
// Schedule per iteration n (buffers alternate; H overwrites Vc in place):
//   ds_write st -> buf[n&1]     (vmcnt wait here touches only the prefetch loads:
//                                they are OLDER than the epilogue stores of n-1)
//   softbar | GEMM1 | softbar | H-write | softbar | issue prefetch(n+1) | GEMM2 | stores
// Stores and prefetch loads are never drained by a barrier (lgkmcnt-only barriers).
__global__ __launch_bounds__(512, 4) void k_score(
    const bf16* __restrict__ xp,    // [16][128][128]
    const bf16* __restrict__ zp,    // [16][128][128]
    const bf16* __restrict__ V,     // [16][128][16512]
    float* __restrict__ out)        // [16][128][128][128]  (b,x,y,z)
{
    __shared__ __align__(16) bf16 Vl[2][129 * 136];  // V tile [i][k] / H tile [z][i]
    __shared__ float Hb[128];                        // H[z][128]
    const int tid = threadIdx.x;
    const int wv = tid >> 6, lane = tid & 63, quad = lane >> 4, lr = lane & 15;
    const int r0 = wv * 16 + lr;                     // wave-owned row (z in G1, x in G2)

    const int it0 = blockIdx.x * 4;
    const int b = it0 >> 7;                          // constant for all 4 iterations
    const int y0 = it0 & 127;                        // y = y0 + n

    const bf16* Zb = zp + b * 16384;
    const bf16* Xb = xp + b * 16384;
    const bf16* Vbase = V + (b * 128 + y0) * 16512;

    // prelude: issue iteration-0 V loads, then loop-invariant fragments
    bf16x8 st[4], st4;
#pragma unroll
    for (int q = 0; q < 8; q++) st4[q] = (bf16)0.f;
#pragma unroll
    for (int u = 0; u < 4; u++) st[u] = *(const bf16x8*)(Vbase + (tid + u * 512) * 8);
    if (tid < 16) st4 = *(const bf16x8*)(Vbase + (2048 + tid) * 8);

    bf16x8 bz[4], bxf[4];
#pragma unroll
    for (int kw = 0; kw < 4; kw++) bz[kw] = *(const bf16x8*)(Zb + r0 * 128 + kw * 32 + quad * 8);
#pragma unroll
    for (int iw = 0; iw < 4; iw++) bxf[iw] = *(const bf16x8*)(Xb + r0 * 128 + iw * 32 + quad * 8);

#pragma unroll 1
    for (int n = 0; n < 4; n++) {
        bf16* Bc = &Vl[n & 1][0];      // this iteration's V tile, then H tile

        // stage this iteration's V (loads were issued last iteration / prelude)
#pragma unroll
        for (int u = 0; u < 4; u++) {
            int c = tid + u * 512;
            *(bf16x8*)(Bc + (c >> 4) * 136 + (c & 15) * 8) = st[u];
        }
        if (tid < 16) *(bf16x8*)(Bc + 128 * 136 + tid * 8) = st4;
        soft_barrier();   // V tile visible to all waves

        // ---- GEMM1: D[row=i][col=z], wave owns z in [wv*16, wv*16+16) ----
        f32x4 acc1[9];
#pragma unroll
        for (int it = 0; it < 9; it++) acc1[it] = zero4();

#pragma unroll
        for (int kw = 0; kw < 4; kw++) {
#pragma unroll
            for (int it = 0; it < 8; it++) {
                bf16x8 af = *(const bf16x8*)(Bc + (it * 16 + lr) * 136 + kw * 32 + quad * 8);
                acc1[it] = MFMA(af, bz[kw], acc1[it]);
            }
            bf16x8 a8;
#pragma unroll
            for (int q = 0; q < 8; q++) a8[q] = (bf16)0.f;
            if (lr == 0) a8 = *(const bf16x8*)(Bc + 128 * 136 + kw * 32 + quad * 8);
            acc1[8] = MFMA(a8, bz[kw], acc1[8]);
        }
        soft_barrier();   // all V reads of Bc done; region reusable for H

        // H -> LDS (reg r = consecutive i), row stride 136; overwrites Bc in place
#pragma unroll
        for (int it = 0; it < 8; it++) {
            int i = it * 16 + quad * 4;
            bf16x4 o;
            o[0] = (bf16)acc1[it][0];
            o[1] = (bf16)acc1[it][1];
            o[2] = (bf16)acc1[it][2];
            o[3] = (bf16)acc1[it][3];
            *(bf16x4*)(Bc + r0 * 136 + i) = o;
        }
        if (quad == 0) Hb[r0] = acc1[8][0];   // bias row i=128 lives in D row 0
        soft_barrier();   // H tile visible

        // prefetch next V row: issued BEFORE the epilogue stores, so next
        // iteration's ds_write waits only these loads, not the stores.
        if (n < 3) {
            const bf16* Vnx = Vbase + (n + 1) * 16512;
#pragma unroll
            for (int u = 0; u < 4; u++) st[u] = *(const bf16x8*)(Vnx + (tid + u * 512) * 8);
            if (tid < 16) st4 = *(const bf16x8*)(Vnx + (2048 + tid) * 8);
        }

        // ---- GEMM2: D[row=z][col=x], wave owns x in [wv*16, wv*16+16) ----
        f32x4 acc2[8];
#pragma unroll
        for (int zt = 0; zt < 8; zt++) acc2[zt] = zero4();

#pragma unroll
        for (int iw = 0; iw < 4; iw++) {
#pragma unroll
            for (int zt = 0; zt < 8; zt++) {
                bf16x8 ah = *(const bf16x8*)(Bc + (zt * 16 + lr) * 136 + iw * 32 + quad * 8);
                acc2[zt] = MFMA(ah, bxf[iw], acc2[zt]);
            }
        }
        // epilogue: f32x4 stores (left in flight across the next soft barrier)
#pragma unroll
        for (int zt = 0; zt < 8; zt++) {
            int zb = zt * 16 + quad * 4;
            f32x4 hb = *(const f32x4*)(&Hb[zb]);
            f32x4 o;
            o[0] = acc2[zt][0] + hb[0];
            o[1] = acc2[zt][1] + hb[1];
            o[2] = acc2[zt][2] + hb[2];
            o[3] = acc2[zt][3] + hb[3];
            *(f32x4*)(out + (((b * 128 + r0) * 128 + (y0 + n)) * 128 + zb)) = o;
        }
    }
}

extern "C" void kernel_launch(void* const* d_in, const int* in_sizes, int n_in,
                              void* d_out, int out_size, void* d_ws, size_t ws_size,
                              hipStream_t stream) {
    const float* x   = (const float*)d_in[0];
    const float* xsp = (const float*)d_in[1];
    const float* Wx  = (const float*)d_in[2];
    const float* bx  = (const float*)d_in[3];
    const float* Wy  = (const float*)d_in[4];
    const float* by  = (const float*)d_in[5];
    const float* Wz  = (const float*)d_in[6];
    const float* bz  = (const float*)d_in[7];
    const float* W3  = (const float*)d_in[8];
    float* out = (float*)d_out;

    char* ws = (char*)d_ws;
    bf16*  xspb   = (bf16*)(ws);                   // 4 MiB
    bf16*  xb     = (bf16*)(ws + 4194304);         // 4 MiB
    bf16*  wbf    = (bf16*)(ws + 8388608);         // 768 KiB
    bf16*  w3b    = (bf16*)(ws + 9175040);         // 16512*136*2 = 4.28 MiB
    bf16*  pout   = (bf16*)(ws + 13666304);        // 3*2048*128*2 = 1.5 MiB (xp,yp,zp)
    bf16*  V      = (bf16*)(ws + 15239168);        // 16*128*16512*2 = 64.5 MiB
    float* w3bias = (float*)(ws + 82872320);       // 66 KB

    k_prep<<<3184, 256, 0, stream>>>(x, xsp, Wx, Wy, Wz, W3, xb, xspb, wbf, w3b, w3bias);
    k_mlp<<<dim3(128, 3), 256, 0, stream>>>(xspb, xb, wbf, bx, by, bz, pout);
    k_vgemm<<<dim3(129, 16), 256, 0, stream>>>(pout + 262144 /*yp*/, w3b, w3bias, V);
    k_score<<<512, 512, 0, stream>>>(pout /*xp*/, pout + 524288 /*zp*/, V, out);
}

// Round 5
// 245.835 us; speedup vs baseline: 1.0335x; 1.0261x over previous
//
#include <hip/hip_runtime.h>

typedef __bf16 bf16;
typedef __bf16 bf16x8 __attribute__((ext_vector_type(8)));
typedef __bf16 bf16x4 __attribute__((ext_vector_type(4)));
typedef float f32x4 __attribute__((ext_vector_type(4)));

#define MFMA(a, b, c) __builtin_amdgcn_mfma_f32_16x16x32_bf16((a), (b), (c), 0, 0, 0)

static __device__ __forceinline__ f32x4 zero4() {
    f32x4 z; z[0] = 0.f; z[1] = 0.f; z[2] = 0.f; z[3] = 0.f; return z;
}

// LDS-only barrier (see k_score notes): all cross-wave deps at these barriers are
// LDS-carried; leaves global loads/stores in flight, unlike __syncthreads().
static __device__ __forceinline__ void soft_barrier() {
    __builtin_amdgcn_sched_barrier(0);
    asm volatile("s_waitcnt lgkmcnt(0)" ::: "memory");
    __builtin_amdgcn_s_barrier();
    __builtin_amdgcn_sched_barrier(0);
}

// ---------------- prep: W (bf16) + W3 (bf16, padded) conversions ----------------
// x/xsp conversion removed: k_mlp reads f32 directly (saves a full HBM round-trip).
// W3 rows are 129 f32 = 516 B -> odd rows are NOT 16B-aligned; use scalar dword
// loads (always 4-aligned) instead of a mis-asserted float4.
__global__ __launch_bounds__(256) void k_prep(
    const float* __restrict__ Wx, const float* __restrict__ Wy, const float* __restrict__ Wz,
    const float* __restrict__ W3,
    bf16* __restrict__ wbf, bf16* __restrict__ w3b, float* __restrict__ w3bias)
{
    const int b = blockIdx.x, t = threadIdx.x;
    if (b < 96) {
        int proj = b >> 5;
        const float* src = (proj == 0) ? Wx : (proj == 1) ? Wy : Wz;
        bf16* dst = wbf + proj * 131072;
        int o = (b & 31) * 4096 + t * 16;
#pragma unroll
        for (int u = 0; u < 4; u++) {
            float4 v = *(const float4*)(src + o + u * 4);
            bf16x4 w; w[0] = (bf16)v.x; w[1] = (bf16)v.y; w[2] = (bf16)v.z; w[3] = (bf16)v.w;
            *(bf16x4*)(dst + o + u * 4) = w;
        }
    } else {
        int nb = b - 96;                     // 0..2063
        int n = nb * 8 + (t >> 5);           // row of W3 (i*128+k), < 16512
        int c = t & 31;
        const float* row = W3 + n * 129;
        float v0 = row[4 * c + 0];
        float v1 = row[4 * c + 1];
        float v2 = row[4 * c + 2];
        float v3 = row[4 * c + 3];
        bf16x4 w;
        w[0] = (bf16)v0; w[1] = (bf16)v1; w[2] = (bf16)v2; w[3] = (bf16)v3;
        *(bf16x4*)(w3b + n * 136 + 4 * c) = w;   // 272B row stride: 8B-aligned ok
        if (c == 0) w3bias[n] = row[128];
    }
}

// ---------------- MLP: pout[proj][m][p] = leaky_relu(A @ W^T + b) ----------------
// A (x or x_span) read as f32 straight from the input buffers, converted ONCE per
// block into an LDS bf16 tile (row stride 1032 -> 2-way bank alias, free).
// Inner MFMA loop identical to the verified version, B-fragments now from LDS.
__global__ __launch_bounds__(256) void k_mlp(
    const float* __restrict__ xsp, const float* __restrict__ x,
    const bf16* __restrict__ wbf,
    const float* __restrict__ bx, const float* __restrict__ by, const float* __restrict__ bz,
    bf16* __restrict__ pout)
{
    __shared__ bf16 Al[16 * 1032];
    const int proj = blockIdx.y;
    const float* A = (proj == 2) ? x : xsp;
    const bf16* W = wbf + proj * 131072;
    const float* bias = (proj == 0) ? bx : (proj == 1) ? by : bz;
    bf16* out = pout + proj * 262144;

    const int tid = threadIdx.x;
    const int wv = tid >> 6, lane = tid & 63, quad = lane >> 4, lr = lane & 15;
    const int m0 = blockIdx.x * 16;

    // stage A tile (rows m0..m0+15) f32 -> bf16 LDS
    {
        const float* Asrc = A + m0 * 1024;
        const int rr = tid >> 7, cc = (tid & 127) * 8;
#pragma unroll
        for (int i = 0; i < 8; i++) {
            int r = i * 2 + rr;
            float4 v0 = *(const float4*)(Asrc + r * 1024 + cc);
            float4 v1 = *(const float4*)(Asrc + r * 1024 + cc + 4);
            bf16x8 w;
            w[0] = (bf16)v0.x; w[1] = (bf16)v0.y; w[2] = (bf16)v0.z; w[3] = (bf16)v0.w;
            w[4] = (bf16)v1.x; w[5] = (bf16)v1.y; w[6] = (bf16)v1.z; w[7] = (bf16)v1.w;
            *(bf16x8*)(&Al[r * 1032 + cc]) = w;
        }
    }
    __syncthreads();

    f32x4 acc[2];
    acc[0] = zero4(); acc[1] = zero4();

    const bf16* brow = Al + lr * 1032 + quad * 8;
    const bf16* arow = W + (wv * 16 + lr) * 1024 + quad * 8;

#pragma unroll 4
    for (int kw = 0; kw < 32; kw++) {
        bf16x8 bfr = *(const bf16x8*)(brow + kw * 32);
        bf16x8 a0 = *(const bf16x8*)(arow + kw * 32);
        bf16x8 a1 = *(const bf16x8*)(arow + 65536 + kw * 32);
        acc[0] = MFMA(a0, bfr, acc[0]);
        acc[1] = MFMA(a1, bfr, acc[1]);
    }
#pragma unroll
    for (int s = 0; s < 2; s++) {
        int p = (wv + s * 4) * 16 + quad * 4;
        float4 bv = *(const float4*)(bias + p);
        int m = m0 + lr;
        bf16x4 o;
        float v0 = acc[s][0] + bv.x; o[0] = (bf16)(v0 > 0.f ? v0 : 0.1f * v0);
        float v1 = acc[s][1] + bv.y; o[1] = (bf16)(v1 > 0.f ? v1 : 0.1f * v1);
        float v2 = acc[s][2] + bv.z; o[2] = (bf16)(v2 > 0.f ? v2 : 0.1f * v2);
        float v3 = acc[s][3] + bv.w; o[3] = (bf16)(v3 > 0.f ? v3 : 0.1f * v3);
        *(bf16x4*)(out + m * 128 + p) = o;
    }
}

// ---------------- V[b][y][n=(i*128+k)] = sum_j yp[b,y,j]*W3[n,j] + w3bias[n] ----------------
__global__ __launch_bounds__(256, 4) void k_vgemm(
    const bf16* __restrict__ yp,     // [16][128][128]
    const bf16* __restrict__ w3b,    // [16512][136]
    const float* __restrict__ w3bias,// [16512]
    bf16* __restrict__ V)            // [16][128][16512]
{
    __shared__ bf16 Vt[128 * 136];   // [y][n_local], ld=136
    const int b = blockIdx.y;
    const int n0 = blockIdx.x * 128;
    const int tid = threadIdx.x;
    const int wv = tid >> 6, lane = tid & 63, quad = lane >> 4, lr = lane & 15;
    const int y0 = wv * 32;

    const bf16* Ab = yp + b * 16384;

    f32x4 acc[8][2];
#pragma unroll
    for (int nt = 0; nt < 8; nt++) { acc[nt][0] = zero4(); acc[nt][1] = zero4(); }

#pragma unroll
    for (int kw = 0; kw < 4; kw++) {
        bf16x8 b0 = *(const bf16x8*)(Ab + (y0 + lr) * 128 + kw * 32 + quad * 8);
        bf16x8 b1 = *(const bf16x8*)(Ab + (y0 + 16 + lr) * 128 + kw * 32 + quad * 8);
#pragma unroll
        for (int nt = 0; nt < 8; nt++) {
            bf16x8 af = *(const bf16x8*)(w3b + (n0 + nt * 16 + lr) * 136 + kw * 32 + quad * 8);
            acc[nt][0] = MFMA(af, b0, acc[nt][0]);
            acc[nt][1] = MFMA(af, b1, acc[nt][1]);
        }
    }
#pragma unroll
    for (int nt = 0; nt < 8; nt++) {
        int nl = nt * 16 + quad * 4;
        float4 bv = *(const float4*)(w3bias + n0 + nl);
#pragma unroll
        for (int s = 0; s < 2; s++) {
            int y = y0 + s * 16 + lr;
            bf16x4 o;
            o[0] = (bf16)(acc[nt][s][0] + bv.x);
            o[1] = (bf16)(acc[nt][s][1] + bv.y);
            o[2] = (bf16)(acc[nt][s][2] + bv.z);
            o[3] = (bf16)(acc[nt][s][3] + bv.w);
            *(bf16x4*)(&Vt[y * 136 + nl]) = o;
        }
    }
    __syncthreads();
    const int yr = tid >> 4, nn = (tid & 15) * 8;
#pragma unroll
    for (int pass = 0; pass < 8; pass++) {
        int y = pass * 16 + yr;
        bf16x8 v = *(const bf16x8*)(&Vt[y * 136 + nn]);
        *(bf16x8*)(V + (b * 128 + y) * 16512 + n0 + nn) = v;
    }
}

// ---------------- k_score: persistent blocks, soft-barrier software pipeline ----------------
// (unchanged from round 4 -- verified; near its HBM floor of ~31 us)
__global__ __launch_bounds__(512, 4) void k_score(
    const bf16* __restrict__ xp,    // [16][128][128]
    const bf16* __restrict__ zp,    // [16][128][128]
    const bf16* __restrict__ V,     // [16][128][16512]
    float* __restrict__ out)        // [16][128][128][128]  (b,x,y,z)
{
    __shared__ __align__(16) bf16 Vl[2][129 * 136];  // V tile [i][k] / H tile [z][i]
    __shared__ float Hb[128];                        // H[z][128]
    const int tid = threadIdx.x;
    const int wv = tid >> 6, lane = tid & 63, quad = lane >> 4, lr = lane & 15;
    const int r0 = wv * 16 + lr;                     // wave-owned row (z in G1, x in G2)

    const int it0 = blockIdx.x * 4;
    const int b = it0 >> 7;                          // constant for all 4 iterations
    const int y0 = it0 & 127;                        // y = y0 + n

    const bf16* Zb = zp + b * 16384;
    const bf16* Xb = xp + b * 16384;
    const bf16* Vbase = V + (b * 128 + y0) * 16512;

    // prelude: issue iteration-0 V loads, then loop-invariant fragments
    bf16x8 st[4], st4;
#pragma unroll
    for (int q = 0; q < 8; q++) st4[q] = (bf16)0.f;
#pragma unroll
    for (int u = 0; u < 4; u++) st[u] = *(const bf16x8*)(Vbase + (tid + u * 512) * 8);
    if (tid < 16) st4 = *(const bf16x8*)(Vbase + (2048 + tid) * 8);

    bf16x8 bz[4], bxf[4];
#pragma unroll
    for (int kw = 0; kw < 4; kw++) bz[kw] = *(const bf16x8*)(Zb + r0 * 128 + kw * 32 + quad * 8);
#pragma unroll
    for (int iw = 0; iw < 4; iw++) bxf[iw] = *(const bf16x8*)(Xb + r0 * 128 + iw * 32 + quad * 8);

#pragma unroll 1
    for (int n = 0; n < 4; n++) {
        bf16* Bc = &Vl[n & 1][0];      // this iteration's V tile, then H tile

        // stage this iteration's V (loads were issued last iteration / prelude)
#pragma unroll
        for (int u = 0; u < 4; u++) {
            int c = tid + u * 512;
            *(bf16x8*)(Bc + (c >> 4) * 136 + (c & 15) * 8) = st[u];
        }
        if (tid < 16) *(bf16x8*)(Bc + 128 * 136 + tid * 8) = st4;
        soft_barrier();   // V tile visible to all waves

        // ---- GEMM1: D[row=i][col=z], wave owns z in [wv*16, wv*16+16) ----
        f32x4 acc1[9];
#pragma unroll
        for (int it = 0; it < 9; it++) acc1[it] = zero4();

#pragma unroll
        for (int kw = 0; kw < 4; kw++) {
#pragma unroll
            for (int it = 0; it < 8; it++) {
                bf16x8 af = *(const bf16x8*)(Bc + (it * 16 + lr) * 136 + kw * 32 + quad * 8);
                acc1[it] = MFMA(af, bz[kw], acc1[it]);
            }
            bf16x8 a8;
#pragma unroll
            for (int q = 0; q < 8; q++) a8[q] = (bf16)0.f;
            if (lr == 0) a8 = *(const bf16x8*)(Bc + 128 * 136 + kw * 32 + quad * 8);
            acc1[8] = MFMA(a8, bz[kw], acc1[8]);
        }
        soft_barrier();   // all V reads of Bc done; region reusable for H

        // H -> LDS (reg r = consecutive i), row stride 136; overwrites Bc in place
#pragma unroll
        for (int it = 0; it < 8; it++) {
            int i = it * 16 + quad * 4;
            bf16x4 o;
            o[0] = (bf16)acc1[it][0];
            o[1] = (bf16)acc1[it][1];
            o[2] = (bf16)acc1[it][2];
            o[3] = (bf16)acc1[it][3];
            *(bf16x4*)(Bc + r0 * 136 + i) = o;
        }
        if (quad == 0) Hb[r0] = acc1[8][0];   // bias row i=128 lives in D row 0
        soft_barrier();   // H tile visible

        // prefetch next V row (before the epilogue stores)
        if (n < 3) {
            const bf16* Vnx = Vbase + (n + 1) * 16512;
#pragma unroll
            for (int u = 0; u < 4; u++) st[u] = *(const bf16x8*)(Vnx + (tid + u * 512) * 8);
            if (tid < 16) st4 = *(const bf16x8*)(Vnx + (2048 + tid) * 8);
        }

        // ---- GEMM2: D[row=z][col=x], wave owns x in [wv*16, wv*16+16) ----
        f32x4 acc2[8];
#pragma unroll
        for (int zt = 0; zt < 8; zt++) acc2[zt] = zero4();

#pragma unroll
        for (int iw = 0; iw < 4; iw++) {
#pragma unroll
            for (int zt = 0; zt < 8; zt++) {
                bf16x8 ah = *(const bf16x8*)(Bc + (zt * 16 + lr) * 136 + iw * 32 + quad * 8);
                acc2[zt] = MFMA(ah, bxf[iw], acc2[zt]);
            }
        }
        // epilogue: f32x4 stores (left in flight across the next soft barrier)
#pragma unroll
        for (int zt = 0; zt < 8; zt++) {
            int zb = zt * 16 + quad * 4;
            f32x4 hb = *(const f32x4*)(&Hb[zb]);
            f32x4 o;
            o[0] = acc2[zt][0] + hb[0];
            o[1] = acc2[zt][1] + hb[1];
            o[2] = acc2[zt][2] + hb[2];
            o[3] = acc2[zt][3] + hb[3];
            *(f32x4*)(out + (((b * 128 + r0) * 128 + (y0 + n)) * 128 + zb)) = o;
        }
    }
}

extern "C" void kernel_launch(void* const* d_in, const int* in_sizes, int n_in,
                              void* d_out, int out_size, void* d_ws, size_t ws_size,
                              hipStream_t stream) {
    const float* x   = (const float*)d_in[0];
    const float* xsp = (const float*)d_in[1];
    const float* Wx  = (const float*)d_in[2];
    const float* bx  = (const float*)d_in[3];
    const float* Wy  = (const float*)d_in[4];
    const float* by  = (const float*)d_in[5];
    const float* Wz  = (const float*)d_in[6];
    const float* bz  = (const float*)d_in[7];
    const float* W3  = (const float*)d_in[8];
    float* out = (float*)d_out;

    char* ws = (char*)d_ws;
    // (offsets kept from the verified layout; xspb/xb slots now unused)
    bf16*  wbf    = (bf16*)(ws + 8388608);         // 768 KiB
    bf16*  w3b    = (bf16*)(ws + 9175040);         // 16512*136*2 = 4.28 MiB
    bf16*  pout   = (bf16*)(ws + 13666304);        // 3*2048*128*2 = 1.5 MiB (xp,yp,zp)
    bf16*  V      = (bf16*)(ws + 15239168);        // 16*128*16512*2 = 64.5 MiB
    float* w3bias = (float*)(ws + 82872320);       // 66 KB

    k_prep<<<2160, 256, 0, stream>>>(Wx, Wy, Wz, W3, wbf, w3b, w3bias);
    k_mlp<<<dim3(128, 3), 256, 0, stream>>>(xsp, x, wbf, bx, by, bz, pout);
    k_vgemm<<<dim3(129, 16), 256, 0, stream>>>(pout + 262144 /*yp*/, w3b, w3bias, V);
    k_score<<<512, 512, 0, stream>>>(pout /*xp*/, pout + 524288 /*zp*/, V, out);
}

// Round 6
// 240.892 us; speedup vs baseline: 1.0547x; 1.0205x over previous
//
#include <hip/hip_runtime.h>

typedef __bf16 bf16;
typedef __bf16 bf16x8 __attribute__((ext_vector_type(8)));
typedef __bf16 bf16x4 __attribute__((ext_vector_type(4)));
typedef float f32x4 __attribute__((ext_vector_type(4)));

#define MFMA(a, b, c) __builtin_amdgcn_mfma_f32_16x16x32_bf16((a), (b), (c), 0, 0, 0)

static __device__ __forceinline__ f32x4 zero4() {
    f32x4 z; z[0] = 0.f; z[1] = 0.f; z[2] = 0.f; z[3] = 0.f; return z;
}

// LDS-only barrier: all cross-wave deps at these barriers are LDS-carried;
// leaves global loads/stores in flight, unlike __syncthreads().
static __device__ __forceinline__ void soft_barrier() {
    __builtin_amdgcn_sched_barrier(0);
    asm volatile("s_waitcnt lgkmcnt(0)" ::: "memory");
    __builtin_amdgcn_s_barrier();
    __builtin_amdgcn_sched_barrier(0);
}

// ---------------- prep: W (bf16) + W3 (bf16, padded) conversions ----------------
__global__ __launch_bounds__(256) void k_prep(
    const float* __restrict__ Wx, const float* __restrict__ Wy, const float* __restrict__ Wz,
    const float* __restrict__ W3,
    bf16* __restrict__ wbf, bf16* __restrict__ w3b, float* __restrict__ w3bias)
{
    const int b = blockIdx.x, t = threadIdx.x;
    if (b < 96) {
        int proj = b >> 5;
        const float* src = (proj == 0) ? Wx : (proj == 1) ? Wy : Wz;
        bf16* dst = wbf + proj * 131072;
        int o = (b & 31) * 4096 + t * 16;
#pragma unroll
        for (int u = 0; u < 4; u++) {
            float4 v = *(const float4*)(src + o + u * 4);
            bf16x4 w; w[0] = (bf16)v.x; w[1] = (bf16)v.y; w[2] = (bf16)v.z; w[3] = (bf16)v.w;
            *(bf16x4*)(dst + o + u * 4) = w;
        }
    } else {
        int nb = b - 96;                     // 0..2063
        int n = nb * 8 + (t >> 5);           // row of W3 (i*128+k), < 16512
        int c = t & 31;
        const float* row = W3 + n * 129;
        float v0 = row[4 * c + 0];
        float v1 = row[4 * c + 1];
        float v2 = row[4 * c + 2];
        float v3 = row[4 * c + 3];
        bf16x4 w;
        w[0] = (bf16)v0; w[1] = (bf16)v1; w[2] = (bf16)v2; w[3] = (bf16)v3;
        *(bf16x4*)(w3b + n * 136 + 4 * c) = w;
        if (c == 0) w3bias[n] = row[128];
    }
}

// ---------------- MLP: pout[proj][m][p] = leaky_relu(A @ W^T + b) ----------------
__global__ __launch_bounds__(256) void k_mlp(
    const float* __restrict__ xsp, const float* __restrict__ x,
    const bf16* __restrict__ wbf,
    const float* __restrict__ bx, const float* __restrict__ by, const float* __restrict__ bz,
    bf16* __restrict__ pout)
{
    __shared__ bf16 Al[16 * 1032];
    const int proj = blockIdx.y;
    const float* A = (proj == 2) ? x : xsp;
    const bf16* W = wbf + proj * 131072;
    const float* bias = (proj == 0) ? bx : (proj == 1) ? by : bz;
    bf16* out = pout + proj * 262144;

    const int tid = threadIdx.x;
    const int wv = tid >> 6, lane = tid & 63, quad = lane >> 4, lr = lane & 15;
    const int m0 = blockIdx.x * 16;

    {
        const float* Asrc = A + m0 * 1024;
        const int rr = tid >> 7, cc = (tid & 127) * 8;
#pragma unroll
        for (int i = 0; i < 8; i++) {
            int r = i * 2 + rr;
            float4 v0 = *(const float4*)(Asrc + r * 1024 + cc);
            float4 v1 = *(const float4*)(Asrc + r * 1024 + cc + 4);
            bf16x8 w;
            w[0] = (bf16)v0.x; w[1] = (bf16)v0.y; w[2] = (bf16)v0.z; w[3] = (bf16)v0.w;
            w[4] = (bf16)v1.x; w[5] = (bf16)v1.y; w[6] = (bf16)v1.z; w[7] = (bf16)v1.w;
            *(bf16x8*)(&Al[r * 1032 + cc]) = w;
        }
    }
    __syncthreads();

    f32x4 acc[2];
    acc[0] = zero4(); acc[1] = zero4();

    const bf16* brow = Al + lr * 1032 + quad * 8;
    const bf16* arow = W + (wv * 16 + lr) * 1024 + quad * 8;

#pragma unroll 4
    for (int kw = 0; kw < 32; kw++) {
        bf16x8 bfr = *(const bf16x8*)(brow + kw * 32);
        bf16x8 a0 = *(const bf16x8*)(arow + kw * 32);
        bf16x8 a1 = *(const bf16x8*)(arow + 65536 + kw * 32);
        acc[0] = MFMA(a0, bfr, acc[0]);
        acc[1] = MFMA(a1, bfr, acc[1]);
    }
#pragma unroll
    for (int s = 0; s < 2; s++) {
        int p = (wv + s * 4) * 16 + quad * 4;
        float4 bv = *(const float4*)(bias + p);
        int m = m0 + lr;
        bf16x4 o;
        float v0 = acc[s][0] + bv.x; o[0] = (bf16)(v0 > 0.f ? v0 : 0.1f * v0);
        float v1 = acc[s][1] + bv.y; o[1] = (bf16)(v1 > 0.f ? v1 : 0.1f * v1);
        float v2 = acc[s][2] + bv.z; o[2] = (bf16)(v2 > 0.f ? v2 : 0.1f * v2);
        float v3 = acc[s][3] + bv.w; o[3] = (bf16)(v3 > 0.f ? v3 : 0.1f * v3);
        *(bf16x4*)(out + m * 128 + p) = o;
    }
}

// ---------------- V[b][y][n=(i*128+k)] = sum_j yp[b,y,j]*W3[n,j] + w3bias[n] ----------------
// Grid (16,129): b = blockIdx.x -> the 16 blocks sharing one w3b slice are
// dispatch-adjacent (L2/L3-hot) instead of 129 apart (16x HBM refetch).
__global__ __launch_bounds__(256, 4) void k_vgemm(
    const bf16* __restrict__ yp,     // [16][128][128]
    const bf16* __restrict__ w3b,    // [16512][136]
    const float* __restrict__ w3bias,// [16512]
    bf16* __restrict__ V)            // [16][128][16512]
{
    __shared__ bf16 Vt[128 * 136];   // [y][n_local], ld=136
    const int b = blockIdx.x;
    const int n0 = blockIdx.y * 128;
    const int tid = threadIdx.x;
    const int wv = tid >> 6, lane = tid & 63, quad = lane >> 4, lr = lane & 15;
    const int y0 = wv * 32;

    const bf16* Ab = yp + b * 16384;

    f32x4 acc[8][2];
#pragma unroll
    for (int nt = 0; nt < 8; nt++) { acc[nt][0] = zero4(); acc[nt][1] = zero4(); }

#pragma unroll
    for (int kw = 0; kw < 4; kw++) {
        bf16x8 b0 = *(const bf16x8*)(Ab + (y0 + lr) * 128 + kw * 32 + quad * 8);
        bf16x8 b1 = *(const bf16x8*)(Ab + (y0 + 16 + lr) * 128 + kw * 32 + quad * 8);
#pragma unroll
        for (int nt = 0; nt < 8; nt++) {
            bf16x8 af = *(const bf16x8*)(w3b + (n0 + nt * 16 + lr) * 136 + kw * 32 + quad * 8);
            acc[nt][0] = MFMA(af, b0, acc[nt][0]);
            acc[nt][1] = MFMA(af, b1, acc[nt][1]);
        }
    }
#pragma unroll
    for (int nt = 0; nt < 8; nt++) {
        int nl = nt * 16 + quad * 4;
        float4 bv = *(const float4*)(w3bias + n0 + nl);
#pragma unroll
        for (int s = 0; s < 2; s++) {
            int y = y0 + s * 16 + lr;
            bf16x4 o;
            o[0] = (bf16)(acc[nt][s][0] + bv.x);
            o[1] = (bf16)(acc[nt][s][1] + bv.y);
            o[2] = (bf16)(acc[nt][s][2] + bv.z);
            o[3] = (bf16)(acc[nt][s][3] + bv.w);
            *(bf16x4*)(&Vt[y * 136 + nl]) = o;
        }
    }
    __syncthreads();
    const int yr = tid >> 4, nn = (tid & 15) * 8;
#pragma unroll
    for (int pass = 0; pass < 8; pass++) {
        int y = pass * 16 + yr;
        bf16x8 v = *(const bf16x8*)(&Vt[y * 136 + nn]);
        *(bf16x8*)(V + (b * 128 + y) * 16512 + n0 + nn) = v;
    }
}

// ---------------- k_score v3: 256 threads / 4 waves, 32 output cols per wave ----------------
// LDS-redundancy fix: the A-fragment reads (V tile, H tile) are block-uniform, so
// with 8 waves every fragment was read 8x (544 KB/iter from a 33 KB tile -> LDS-
// throughput-bound at ~12cyc/ds_read_b128). 4 waves x 2 B-fragment sets halve the
// ds_read count per MFMA; same MFMA total. VGPR ~195 -> __launch_bounds__(256,2),
// 2 blocks/CU (LDS 2x70.9=141.8 KB <= 160).
__global__ __launch_bounds__(256, 2) void k_score(
    const bf16* __restrict__ xp,    // [16][128][128]
    const bf16* __restrict__ zp,    // [16][128][128]
    const bf16* __restrict__ V,     // [16][128][16512]
    float* __restrict__ out)        // [16][128][128][128]  (b,x,y,z)
{
    __shared__ __align__(16) bf16 Vl[2][129 * 136];  // V tile [i][k] / H tile [z][i]
    __shared__ float Hb[128];                        // H[z][128]
    const int tid = threadIdx.x;
    const int wv = tid >> 6, lane = tid & 63, quad = lane >> 4, lr = lane & 15;
    const int c0 = wv * 32;                          // wave column base (z in G1, x in G2)

    const int it0 = blockIdx.x * 4;
    const int b = it0 >> 7;                          // constant for all 4 iterations
    const int y0 = it0 & 127;                        // y = y0 + n

    const bf16* Zb = zp + b * 16384;
    const bf16* Xb = xp + b * 16384;
    const bf16* Vbase = V + (b * 128 + y0) * 16512;

    // prelude: issue iteration-0 V loads (8 x 16B per thread), then fragments
    bf16x8 st[8], st4;
#pragma unroll
    for (int q = 0; q < 8; q++) st4[q] = (bf16)0.f;
#pragma unroll
    for (int u = 0; u < 8; u++) st[u] = *(const bf16x8*)(Vbase + (tid + u * 256) * 8);
    if (tid < 16) st4 = *(const bf16x8*)(Vbase + (2048 + tid) * 8);

    // loop-invariant zp/xp fragments: wave owns cols c0..c0+31 (two 16-col sets)
    bf16x8 bz[4][2], bxf[4][2];
#pragma unroll
    for (int kw = 0; kw < 4; kw++)
#pragma unroll
        for (int s = 0; s < 2; s++)
            bz[kw][s] = *(const bf16x8*)(Zb + (c0 + s * 16 + lr) * 128 + kw * 32 + quad * 8);
#pragma unroll
    for (int iw = 0; iw < 4; iw++)
#pragma unroll
        for (int s = 0; s < 2; s++)
            bxf[iw][s] = *(const bf16x8*)(Xb + (c0 + s * 16 + lr) * 128 + iw * 32 + quad * 8);

#pragma unroll 1
    for (int n = 0; n < 4; n++) {
        bf16* Bc = &Vl[n & 1][0];      // this iteration's V tile, then H tile

        // stage this iteration's V (loads issued last iteration / prelude)
#pragma unroll
        for (int u = 0; u < 8; u++) {
            int c = tid + u * 256;
            *(bf16x8*)(Bc + (c >> 4) * 136 + (c & 15) * 8) = st[u];
        }
        if (tid < 16) *(bf16x8*)(Bc + 128 * 136 + tid * 8) = st4;
        soft_barrier();   // V tile visible

        // ---- GEMM1: D[row=i][col=z], wave owns z in [c0, c0+32) ----
        f32x4 acc1[9][2];
#pragma unroll
        for (int it = 0; it < 9; it++) { acc1[it][0] = zero4(); acc1[it][1] = zero4(); }

#pragma unroll
        for (int kw = 0; kw < 4; kw++) {
#pragma unroll
            for (int it = 0; it < 8; it++) {
                bf16x8 af = *(const bf16x8*)(Bc + (it * 16 + lr) * 136 + kw * 32 + quad * 8);
                acc1[it][0] = MFMA(af, bz[kw][0], acc1[it][0]);
                acc1[it][1] = MFMA(af, bz[kw][1], acc1[it][1]);
            }
            bf16x8 a8;
#pragma unroll
            for (int q = 0; q < 8; q++) a8[q] = (bf16)0.f;
            if (lr == 0) a8 = *(const bf16x8*)(Bc + 128 * 136 + kw * 32 + quad * 8);
            acc1[8][0] = MFMA(a8, bz[kw][0], acc1[8][0]);
            acc1[8][1] = MFMA(a8, bz[kw][1], acc1[8][1]);
        }
        soft_barrier();   // all V reads done; region reusable for H

        // H -> LDS: thread writes TWO z-rows (c0+lr, c0+16+lr)
#pragma unroll
        for (int it = 0; it < 8; it++) {
            int i = it * 16 + quad * 4;
#pragma unroll
            for (int s = 0; s < 2; s++) {
                bf16x4 o;
                o[0] = (bf16)acc1[it][s][0];
                o[1] = (bf16)acc1[it][s][1];
                o[2] = (bf16)acc1[it][s][2];
                o[3] = (bf16)acc1[it][s][3];
                *(bf16x4*)(Bc + (c0 + s * 16 + lr) * 136 + i) = o;
            }
        }
        if (quad == 0) {
            Hb[c0 + lr]      = acc1[8][0][0];   // bias (i=128) lives in D row 0
            Hb[c0 + 16 + lr] = acc1[8][1][0];
        }
        soft_barrier();   // H tile visible

        // prefetch next V row (before the epilogue stores)
        if (n < 3) {
            const bf16* Vnx = Vbase + (n + 1) * 16512;
#pragma unroll
            for (int u = 0; u < 8; u++) st[u] = *(const bf16x8*)(Vnx + (tid + u * 256) * 8);
            if (tid < 16) st4 = *(const bf16x8*)(Vnx + (2048 + tid) * 8);
        }

        // ---- GEMM2: D[row=z][col=x], wave owns x in [c0, c0+32) ----
        f32x4 acc2[8][2];
#pragma unroll
        for (int zt = 0; zt < 8; zt++) { acc2[zt][0] = zero4(); acc2[zt][1] = zero4(); }

#pragma unroll
        for (int iw = 0; iw < 4; iw++) {
#pragma unroll
            for (int zt = 0; zt < 8; zt++) {
                bf16x8 ah = *(const bf16x8*)(Bc + (zt * 16 + lr) * 136 + iw * 32 + quad * 8);
                acc2[zt][0] = MFMA(ah, bxf[iw][0], acc2[zt][0]);
                acc2[zt][1] = MFMA(ah, bxf[iw][1], acc2[zt][1]);
            }
        }
        // epilogue: x = c0 + s*16 + lr, z = zt*16 + quad*4
#pragma unroll
        for (int zt = 0; zt < 8; zt++) {
            int zb = zt * 16 + quad * 4;
            f32x4 hb = *(const f32x4*)(&Hb[zb]);
#pragma unroll
            for (int s = 0; s < 2; s++) {
                int xx = c0 + s * 16 + lr;
                f32x4 o;
                o[0] = acc2[zt][s][0] + hb[0];
                o[1] = acc2[zt][s][1] + hb[1];
                o[2] = acc2[zt][s][2] + hb[2];
                o[3] = acc2[zt][s][3] + hb[3];
                *(f32x4*)(out + (((b * 128 + xx) * 128 + (y0 + n)) * 128 + zb)) = o;
            }
        }
    }
}

extern "C" void kernel_launch(void* const* d_in, const int* in_sizes, int n_in,
                              void* d_out, int out_size, void* d_ws, size_t ws_size,
                              hipStream_t stream) {
    const float* x   = (const float*)d_in[0];
    const float* xsp = (const float*)d_in[1];
    const float* Wx  = (const float*)d_in[2];
    const float* bx  = (const float*)d_in[3];
    const float* Wy  = (const float*)d_in[4];
    const float* by  = (const float*)d_in[5];
    const float* Wz  = (const float*)d_in[6];
    const float* bz  = (const float*)d_in[7];
    const float* W3  = (const float*)d_in[8];
    float* out = (float*)d_out;

    char* ws = (char*)d_ws;
    bf16*  wbf    = (bf16*)(ws + 8388608);         // 768 KiB
    bf16*  w3b    = (bf16*)(ws + 9175040);         // 16512*136*2 = 4.28 MiB
    bf16*  pout   = (bf16*)(ws + 13666304);        // 3*2048*128*2 = 1.5 MiB (xp,yp,zp)
    bf16*  V      = (bf16*)(ws + 15239168);        // 16*128*16512*2 = 64.5 MiB
    float* w3bias = (float*)(ws + 82872320);       // 66 KB

    k_prep<<<2160, 256, 0, stream>>>(Wx, Wy, Wz, W3, wbf, w3b, w3bias);
    k_mlp<<<dim3(128, 3), 256, 0, stream>>>(xsp, x, wbf, bx, by, bz, pout);
    k_vgemm<<<dim3(16, 129), 256, 0, stream>>>(pout + 262144 /*yp*/, w3b, w3bias, V);
    k_score<<<512, 256, 0, stream>>>(pout /*xp*/, pout + 524288 /*zp*/, V, out);
}